// Round 1
// baseline (9643.460 us; speedup 1.0000x reference)
//
#include <hip/hip_runtime.h>
#include <math.h>

#define N_NODES 100000
#define N_EDGES 1600000
#define HEADS 4

// ---------------- utility kernels ----------------

__global__ void zero_kernel(float* __restrict__ ptr, int n) {
    int i = blockIdx.x * blockDim.x + threadIdx.x;
    if (i < n) ptr[i] = 0.0f;
}

__global__ void deg_kernel(const int* __restrict__ dst, float* __restrict__ deg) {
    int e = blockIdx.x * blockDim.x + threadIdx.x;
    if (e < N_EDGES) atomicAdd(&deg[dst[e]], 1.0f);
}

// ---------------- per-node transform: y = x@W [N,H*FOUT], p = x@U [N,H] ----------------

template<int FIN, int FOUT>
__global__ __launch_bounds__(256) void transform_kernel(
        const float* __restrict__ x,
        const float* __restrict__ W,   // [FIN, HEADS*FOUT]
        const float* __restrict__ U,   // [FIN, HEADS]
        float* __restrict__ y,         // [N, HEADS*FOUT]
        float* __restrict__ p)         // [N, HEADS]
{
    constexpr int HF = HEADS * FOUT;
    __shared__ float Ws[FIN * HF];
    __shared__ float Us[FIN * HEADS];
    for (int i = threadIdx.x; i < FIN * HF; i += blockDim.x) Ws[i] = W[i];
    for (int i = threadIdx.x; i < FIN * HEADS; i += blockDim.x) Us[i] = U[i];
    __syncthreads();

    int n = blockIdx.x * blockDim.x + threadIdx.x;
    if (n >= N_NODES) return;

    float xr[FIN];
    #pragma unroll
    for (int f = 0; f < FIN; f++) xr[f] = x[(size_t)n * FIN + f];

    #pragma unroll
    for (int h = 0; h < HEADS; h++) {
        float acc = 0.0f;
        #pragma unroll
        for (int f = 0; f < FIN; f++) acc += xr[f] * Us[f * HEADS + h];
        p[(size_t)n * HEADS + h] = acc;
    }

    for (int o = 0; o < HF; o++) {
        float acc = 0.0f;
        #pragma unroll
        for (int f = 0; f < FIN; f++) acc += xr[f] * Ws[f * HF + o];
        y[(size_t)n * HF + o] = acc;
    }
}

// ---------------- edge kernel: softmax over heads, combine, scatter-add ----------------

template<int FOUT>
__global__ __launch_bounds__(256) void edge_kernel(
        const int* __restrict__ src, const int* __restrict__ dst,
        const float* __restrict__ y,   // [N, HEADS*FOUT]
        const float* __restrict__ p,   // [N, HEADS]
        const float* __restrict__ c,   // [HEADS]
        float* __restrict__ agg)       // [N, FOUT] (pre-zeroed)
{
    int e = blockIdx.x * blockDim.x + threadIdx.x;
    if (e >= N_EDGES) return;
    int s = src[e], d = dst[e];

    float4 ps = *(const float4*)(p + (size_t)s * HEADS);
    float4 pd = *(const float4*)(p + (size_t)d * HEADS);
    float l0 = ps.x - pd.x + c[0];
    float l1 = ps.y - pd.y + c[1];
    float l2 = ps.z - pd.z + c[2];
    float l3 = ps.w - pd.w + c[3];
    float m = fmaxf(fmaxf(l0, l1), fmaxf(l2, l3));
    float q0 = expf(l0 - m), q1 = expf(l1 - m), q2 = expf(l2 - m), q3 = expf(l3 - m);
    float inv = 1.0f / (q0 + q1 + q2 + q3);
    q0 *= inv; q1 *= inv; q2 *= inv; q3 *= inv;

    const float4* yr = (const float4*)(y + (size_t)s * HEADS * FOUT);
    float* ad = agg + (size_t)d * FOUT;
    constexpr int F4 = FOUT / 4;
    for (int o4 = 0; o4 < F4; o4++) {
        float4 v0 = yr[o4];
        float4 v1 = yr[F4 + o4];
        float4 v2 = yr[2 * F4 + o4];
        float4 v3 = yr[3 * F4 + o4];
        float mx = q0 * v0.x + q1 * v1.x + q2 * v2.x + q3 * v3.x;
        float my = q0 * v0.y + q1 * v1.y + q2 * v2.y + q3 * v3.y;
        float mz = q0 * v0.z + q1 * v1.z + q2 * v2.z + q3 * v3.z;
        float mw = q0 * v0.w + q1 * v1.w + q2 * v2.w + q3 * v3.w;
        atomicAdd(&ad[4 * o4 + 0], mx);
        atomicAdd(&ad[4 * o4 + 1], my);
        atomicAdd(&ad[4 * o4 + 2], mz);
        atomicAdd(&ad[4 * o4 + 3], mw);
    }
}

// ---------------- finalize: mean + bias + relu (in place) ----------------

template<int FOUT>
__global__ void finalize_kernel(float* __restrict__ agg,
                                const float* __restrict__ deg,
                                const float* __restrict__ b)
{
    int i = blockIdx.x * blockDim.x + threadIdx.x;
    if (i >= N_NODES * FOUT) return;
    int n = i / FOUT, o = i - n * FOUT;
    float v = agg[i] / fmaxf(deg[n], 1.0f) + b[o];
    agg[i] = fmaxf(v, 0.0f);
}

// ---------------- fused linear tail: 64->32->16->8->4->1, relu..., sigmoid ----------------

__global__ __launch_bounds__(256) void tail_kernel(
        const float* __restrict__ h,   // [N, 64]
        const float* __restrict__ lw1, const float* __restrict__ lb1,
        const float* __restrict__ lw2, const float* __restrict__ lb2,
        const float* __restrict__ lw3, const float* __restrict__ lb3,
        const float* __restrict__ lw4, const float* __restrict__ lb4,
        const float* __restrict__ lw5, const float* __restrict__ lb5,
        float* __restrict__ out)
{
    __shared__ float w1[64 * 32], w2[32 * 16], w3[16 * 8], w4[8 * 4], w5[4];
    __shared__ float B1[32], B2[16], B3[8], B4[4], B5[1];
    for (int i = threadIdx.x; i < 64 * 32; i += blockDim.x) w1[i] = lw1[i];
    for (int i = threadIdx.x; i < 32 * 16; i += blockDim.x) w2[i] = lw2[i];
    for (int i = threadIdx.x; i < 16 * 8;  i += blockDim.x) w3[i] = lw3[i];
    for (int i = threadIdx.x; i < 8 * 4;   i += blockDim.x) w4[i] = lw4[i];
    for (int i = threadIdx.x; i < 4;       i += blockDim.x) w5[i] = lw5[i];
    for (int i = threadIdx.x; i < 32; i += blockDim.x) B1[i] = lb1[i];
    for (int i = threadIdx.x; i < 16; i += blockDim.x) B2[i] = lb2[i];
    for (int i = threadIdx.x; i < 8;  i += blockDim.x) B3[i] = lb3[i];
    for (int i = threadIdx.x; i < 4;  i += blockDim.x) B4[i] = lb4[i];
    if (threadIdx.x == 0) B5[0] = lb5[0];
    __syncthreads();

    int n = blockIdx.x * blockDim.x + threadIdx.x;
    if (n >= N_NODES) return;

    float a[64];
    #pragma unroll
    for (int i = 0; i < 64; i++) a[i] = h[(size_t)n * 64 + i];

    float t1[32];
    for (int o = 0; o < 32; o++) {
        float acc = B1[o];
        #pragma unroll
        for (int i = 0; i < 64; i++) acc += a[i] * w1[i * 32 + o];
        t1[o] = fmaxf(acc, 0.0f);
    }
    float t2[16];
    for (int o = 0; o < 16; o++) {
        float acc = B2[o];
        #pragma unroll
        for (int i = 0; i < 32; i++) acc += t1[i] * w2[i * 16 + o];
        t2[o] = fmaxf(acc, 0.0f);
    }
    float t3[8];
    for (int o = 0; o < 8; o++) {
        float acc = B3[o];
        #pragma unroll
        for (int i = 0; i < 16; i++) acc += t2[i] * w3[i * 8 + o];
        t3[o] = fmaxf(acc, 0.0f);
    }
    float t4[4];
    for (int o = 0; o < 4; o++) {
        float acc = B4[o];
        #pragma unroll
        for (int i = 0; i < 8; i++) acc += t3[i] * w4[i * 4 + o];
        t4[o] = fmaxf(acc, 0.0f);
    }
    float z = B5[0];
    #pragma unroll
    for (int i = 0; i < 4; i++) z += t4[i] * w5[i];
    out[n] = 1.0f / (1.0f + expf(-z));
}

// ---------------- host launch ----------------

extern "C" void kernel_launch(void* const* d_in, const int* in_sizes, int n_in,
                              void* d_out, int out_size, void* d_ws, size_t ws_size,
                              hipStream_t stream) {
    const float* x   = (const float*)d_in[0];
    const int*   ei  = (const int*)d_in[1];
    const int*   src = ei;
    const int*   dst = ei + N_EDGES;
    const float* U1 = (const float*)d_in[2];  const float* c1 = (const float*)d_in[3];
    const float* W1 = (const float*)d_in[4];  const float* b1 = (const float*)d_in[5];
    const float* U2 = (const float*)d_in[6];  const float* c2 = (const float*)d_in[7];
    const float* W2 = (const float*)d_in[8];  const float* b2 = (const float*)d_in[9];
    const float* U3 = (const float*)d_in[10]; const float* c3 = (const float*)d_in[11];
    const float* W3 = (const float*)d_in[12]; const float* b3 = (const float*)d_in[13];
    const float* lw1 = (const float*)d_in[14]; const float* lb1 = (const float*)d_in[15];
    const float* lw2 = (const float*)d_in[16]; const float* lb2 = (const float*)d_in[17];
    const float* lw3 = (const float*)d_in[18]; const float* lb3 = (const float*)d_in[19];
    const float* lw4 = (const float*)d_in[20]; const float* lb4 = (const float*)d_in[21];
    const float* lw5 = (const float*)d_in[22]; const float* lb5 = (const float*)d_in[23];

    char* ws = (char*)d_ws;
    size_t off = 0;
    auto alloc = [&](size_t bytes) -> float* {
        float* ptr = (float*)(ws + off);
        off += (bytes + 255) & ~(size_t)255;
        return ptr;
    };
    float* deg = alloc((size_t)N_NODES * 4);               // [N]
    float* p   = alloc((size_t)N_NODES * HEADS * 4);       // [N,4]   (reused)
    float* y   = alloc((size_t)N_NODES * 256 * 4);         // [N,256] (reused, max H*Fout)
    float* h1  = alloc((size_t)N_NODES * 16 * 4);          // [N,16]
    float* h2  = alloc((size_t)N_NODES * 32 * 4);          // [N,32]
    float* h3  = alloc((size_t)N_NODES * 64 * 4);          // [N,64]
    (void)ws_size;

    const int B = 256;
    int gN  = (N_NODES + B - 1) / B;
    int gE  = (N_EDGES + B - 1) / B;

    // degree (once)
    zero_kernel<<<gN, B, 0, stream>>>(deg, N_NODES);
    deg_kernel<<<gE, B, 0, stream>>>(dst, deg);

    // ---- conv1: 16 -> 16 ----
    transform_kernel<16, 16><<<gN, B, 0, stream>>>(x, W1, U1, y, p);
    zero_kernel<<<(N_NODES * 16 + B - 1) / B, B, 0, stream>>>(h1, N_NODES * 16);
    edge_kernel<16><<<gE, B, 0, stream>>>(src, dst, y, p, c1, h1);
    finalize_kernel<16><<<(N_NODES * 16 + B - 1) / B, B, 0, stream>>>(h1, deg, b1);

    // ---- conv2: 16 -> 32 ----
    transform_kernel<16, 32><<<gN, B, 0, stream>>>(h1, W2, U2, y, p);
    zero_kernel<<<(N_NODES * 32 + B - 1) / B, B, 0, stream>>>(h2, N_NODES * 32);
    edge_kernel<32><<<gE, B, 0, stream>>>(src, dst, y, p, c2, h2);
    finalize_kernel<32><<<(N_NODES * 32 + B - 1) / B, B, 0, stream>>>(h2, deg, b2);

    // ---- conv3: 32 -> 64 ----
    transform_kernel<32, 64><<<gN, B, 0, stream>>>(h2, W3, U3, y, p);
    zero_kernel<<<(N_NODES * 64 + B - 1) / B, B, 0, stream>>>(h3, N_NODES * 64);
    edge_kernel<64><<<gE, B, 0, stream>>>(src, dst, y, p, c3, h3);
    finalize_kernel<64><<<(N_NODES * 64 + B - 1) / B, B, 0, stream>>>(h3, deg, b3);

    // ---- tail MLP ----
    tail_kernel<<<gN, B, 0, stream>>>(h3, lw1, lb1, lw2, lb2, lw3, lb3,
                                      lw4, lb4, lw5, lb5, (float*)d_out);
}

// Round 2
// 900.452 us; speedup vs baseline: 10.7096x; 10.7096x over previous
//
#include <hip/hip_runtime.h>
#include <math.h>

#define N_NODES 100000
#define N_EDGES 1600000
#define HEADS 4
#define NB ((N_NODES + 255) / 256)   // 391 scan blocks

// ---------------- CSR build kernels ----------------

__global__ void zero_int_kernel(int* __restrict__ ptr, int n) {
    int i = blockIdx.x * blockDim.x + threadIdx.x;
    if (i < n) ptr[i] = 0;
}

__global__ void hist_kernel(const int* __restrict__ dst, int* __restrict__ cnt) {
    int e = blockIdx.x * blockDim.x + threadIdx.x;
    if (e < N_EDGES) atomicAdd(&cnt[dst[e]], 1);
}

// per-block exclusive scan of cnt -> rowptr (block-local), block totals -> blockSums
__global__ __launch_bounds__(256) void scan_block_kernel(
        const int* __restrict__ cnt, int* __restrict__ rowptr, int* __restrict__ blockSums) {
    __shared__ int tmp[256];
    int i = blockIdx.x * 256 + threadIdx.x;
    int v = (i < N_NODES) ? cnt[i] : 0;
    tmp[threadIdx.x] = v;
    __syncthreads();
    for (int off = 1; off < 256; off <<= 1) {
        int t = (threadIdx.x >= off) ? tmp[threadIdx.x - off] : 0;
        __syncthreads();
        tmp[threadIdx.x] += t;
        __syncthreads();
    }
    if (i < N_NODES) rowptr[i] = tmp[threadIdx.x] - v;       // exclusive, block-local
    if (threadIdx.x == 255) blockSums[blockIdx.x] = tmp[255]; // inclusive block total
}

// single-block exclusive scan of blockSums (NB=391 <= 512)
__global__ __launch_bounds__(512) void scan_sums_kernel(int* __restrict__ blockSums) {
    __shared__ int tmp[512];
    int i = threadIdx.x;
    int v = (i < NB) ? blockSums[i] : 0;
    tmp[i] = v;
    __syncthreads();
    for (int off = 1; off < 512; off <<= 1) {
        int t = (i >= off) ? tmp[i - off] : 0;
        __syncthreads();
        tmp[i] += t;
        __syncthreads();
    }
    if (i < NB) blockSums[i] = tmp[i] - v;                   // exclusive
}

__global__ __launch_bounds__(256) void add_offsets_kernel(
        int* __restrict__ rowptr, const int* __restrict__ blockSums) {
    int i = blockIdx.x * 256 + threadIdx.x;
    if (i < N_NODES) rowptr[i] += blockSums[blockIdx.x];
    if (i == 0) rowptr[N_NODES] = N_EDGES;
}

__global__ void scatter_kernel(const int* __restrict__ src, const int* __restrict__ dst,
                               const int* __restrict__ rowptr, int* __restrict__ cnt,
                               int* __restrict__ csr_src) {
    int e = blockIdx.x * blockDim.x + threadIdx.x;
    if (e >= N_EDGES) return;
    int d = dst[e];
    int pos = rowptr[d] + atomicAdd(&cnt[d], 1);
    csr_src[pos] = src[e];
}

// ---------------- per-node transform: y = x@W [N,H*FOUT], p = x@U [N,H] ----------------

template<int FIN, int FOUT>
__global__ __launch_bounds__(256) void transform_kernel(
        const float* __restrict__ x,
        const float* __restrict__ W,   // [FIN, HEADS*FOUT]
        const float* __restrict__ U,   // [FIN, HEADS]
        float* __restrict__ y,         // [N, HEADS*FOUT]
        float* __restrict__ p)         // [N, HEADS]
{
    constexpr int HF = HEADS * FOUT;
    __shared__ float Ws[FIN * HF];
    __shared__ float Us[FIN * HEADS];
    for (int i = threadIdx.x; i < FIN * HF; i += blockDim.x) Ws[i] = W[i];
    for (int i = threadIdx.x; i < FIN * HEADS; i += blockDim.x) Us[i] = U[i];
    __syncthreads();

    int n = blockIdx.x * blockDim.x + threadIdx.x;
    if (n >= N_NODES) return;

    float xr[FIN];
    #pragma unroll
    for (int f = 0; f < FIN; f++) xr[f] = x[(size_t)n * FIN + f];

    #pragma unroll
    for (int h = 0; h < HEADS; h++) {
        float acc = 0.0f;
        #pragma unroll
        for (int f = 0; f < FIN; f++) acc += xr[f] * Us[f * HEADS + h];
        p[(size_t)n * HEADS + h] = acc;
    }

    for (int o = 0; o < HF; o++) {
        float acc = 0.0f;
        #pragma unroll
        for (int f = 0; f < FIN; f++) acc += xr[f] * Ws[f * HF + o];
        y[(size_t)n * HF + o] = acc;
    }
}

// ---------------- gather: per (node, feature), softmax+combine+mean+bias+relu ----------------

template<int FOUT>
__global__ __launch_bounds__(256) void gather_kernel(
        const int* __restrict__ rowptr, const int* __restrict__ csr_src,
        const float* __restrict__ y,   // [N, HEADS*FOUT]
        const float* __restrict__ p,   // [N, HEADS]
        const float* __restrict__ c,   // [HEADS]
        const float* __restrict__ b,   // [FOUT]
        float* __restrict__ outh)      // [N, FOUT]
{
    int t = blockIdx.x * blockDim.x + threadIdx.x;
    int n = t / FOUT;
    int o = t - n * FOUT;
    if (n >= N_NODES) return;

    int beg = rowptr[n], end = rowptr[n + 1];
    float4 pd = *(const float4*)(p + (size_t)n * HEADS);
    float c0 = c[0], c1 = c[1], c2 = c[2], c3 = c[3];

    float acc = 0.0f;
    for (int k = beg; k < end; k++) {
        int s = csr_src[k];
        float4 ps = *(const float4*)(p + (size_t)s * HEADS);
        float l0 = ps.x - pd.x + c0;
        float l1 = ps.y - pd.y + c1;
        float l2 = ps.z - pd.z + c2;
        float l3 = ps.w - pd.w + c3;
        float m = fmaxf(fmaxf(l0, l1), fmaxf(l2, l3));
        float q0 = expf(l0 - m), q1 = expf(l1 - m), q2 = expf(l2 - m), q3 = expf(l3 - m);
        float inv = 1.0f / (q0 + q1 + q2 + q3);
        const float* yr = y + (size_t)s * (HEADS * FOUT) + o;
        acc += inv * (q0 * yr[0] + q1 * yr[FOUT] + q2 * yr[2 * FOUT] + q3 * yr[3 * FOUT]);
    }
    float degf = (float)(end - beg);
    outh[t] = fmaxf(acc / fmaxf(degf, 1.0f) + b[o], 0.0f);
}

// ---------------- fused linear tail: 64->32->16->8->4->1, relu..., sigmoid ----------------

__global__ __launch_bounds__(256) void tail_kernel(
        const float* __restrict__ h,   // [N, 64]
        const float* __restrict__ lw1, const float* __restrict__ lb1,
        const float* __restrict__ lw2, const float* __restrict__ lb2,
        const float* __restrict__ lw3, const float* __restrict__ lb3,
        const float* __restrict__ lw4, const float* __restrict__ lb4,
        const float* __restrict__ lw5, const float* __restrict__ lb5,
        float* __restrict__ out)
{
    __shared__ float w1[64 * 32], w2[32 * 16], w3[16 * 8], w4[8 * 4], w5[4];
    __shared__ float B1[32], B2[16], B3[8], B4[4], B5[1];
    for (int i = threadIdx.x; i < 64 * 32; i += blockDim.x) w1[i] = lw1[i];
    for (int i = threadIdx.x; i < 32 * 16; i += blockDim.x) w2[i] = lw2[i];
    for (int i = threadIdx.x; i < 16 * 8;  i += blockDim.x) w3[i] = lw3[i];
    for (int i = threadIdx.x; i < 8 * 4;   i += blockDim.x) w4[i] = lw4[i];
    for (int i = threadIdx.x; i < 4;       i += blockDim.x) w5[i] = lw5[i];
    for (int i = threadIdx.x; i < 32; i += blockDim.x) B1[i] = lb1[i];
    for (int i = threadIdx.x; i < 16; i += blockDim.x) B2[i] = lb2[i];
    for (int i = threadIdx.x; i < 8;  i += blockDim.x) B3[i] = lb3[i];
    for (int i = threadIdx.x; i < 4;  i += blockDim.x) B4[i] = lb4[i];
    if (threadIdx.x == 0) B5[0] = lb5[0];
    __syncthreads();

    int n = blockIdx.x * blockDim.x + threadIdx.x;
    if (n >= N_NODES) return;

    float a[64];
    #pragma unroll
    for (int i = 0; i < 64; i++) a[i] = h[(size_t)n * 64 + i];

    float t1[32];
    for (int o = 0; o < 32; o++) {
        float acc = B1[o];
        #pragma unroll
        for (int i = 0; i < 64; i++) acc += a[i] * w1[i * 32 + o];
        t1[o] = fmaxf(acc, 0.0f);
    }
    float t2[16];
    for (int o = 0; o < 16; o++) {
        float acc = B2[o];
        #pragma unroll
        for (int i = 0; i < 32; i++) acc += t1[i] * w2[i * 16 + o];
        t2[o] = fmaxf(acc, 0.0f);
    }
    float t3[8];
    for (int o = 0; o < 8; o++) {
        float acc = B3[o];
        #pragma unroll
        for (int i = 0; i < 16; i++) acc += t2[i] * w3[i * 8 + o];
        t3[o] = fmaxf(acc, 0.0f);
    }
    float t4[4];
    for (int o = 0; o < 4; o++) {
        float acc = B4[o];
        #pragma unroll
        for (int i = 0; i < 8; i++) acc += t3[i] * w4[i * 4 + o];
        t4[o] = fmaxf(acc, 0.0f);
    }
    float z = B5[0];
    #pragma unroll
    for (int i = 0; i < 4; i++) z += t4[i] * w5[i];
    out[n] = 1.0f / (1.0f + expf(-z));
}

// ---------------- host launch ----------------

extern "C" void kernel_launch(void* const* d_in, const int* in_sizes, int n_in,
                              void* d_out, int out_size, void* d_ws, size_t ws_size,
                              hipStream_t stream) {
    const float* x   = (const float*)d_in[0];
    const int*   ei  = (const int*)d_in[1];
    const int*   src = ei;
    const int*   dst = ei + N_EDGES;
    const float* U1 = (const float*)d_in[2];  const float* c1 = (const float*)d_in[3];
    const float* W1 = (const float*)d_in[4];  const float* b1 = (const float*)d_in[5];
    const float* U2 = (const float*)d_in[6];  const float* c2 = (const float*)d_in[7];
    const float* W2 = (const float*)d_in[8];  const float* b2 = (const float*)d_in[9];
    const float* U3 = (const float*)d_in[10]; const float* c3 = (const float*)d_in[11];
    const float* W3 = (const float*)d_in[12]; const float* b3 = (const float*)d_in[13];
    const float* lw1 = (const float*)d_in[14]; const float* lb1 = (const float*)d_in[15];
    const float* lw2 = (const float*)d_in[16]; const float* lb2 = (const float*)d_in[17];
    const float* lw3 = (const float*)d_in[18]; const float* lb3 = (const float*)d_in[19];
    const float* lw4 = (const float*)d_in[20]; const float* lb4 = (const float*)d_in[21];
    const float* lw5 = (const float*)d_in[22]; const float* lb5 = (const float*)d_in[23];

    char* ws = (char*)d_ws;
    size_t off = 0;
    auto alloc = [&](size_t bytes) -> void* {
        void* ptr = (void*)(ws + off);
        off += (bytes + 255) & ~(size_t)255;
        return ptr;
    };
    int* cnt       = (int*)alloc((size_t)N_NODES * 4);        // histogram, then scatter cursor
    int* rowptr    = (int*)alloc(((size_t)N_NODES + 1) * 4);
    int* blockSums = (int*)alloc(512 * 4);
    int* csr_src   = (int*)alloc((size_t)N_EDGES * 4);
    float* p  = (float*)alloc((size_t)N_NODES * HEADS * 4);   // [N,4]   (reused)
    float* y  = (float*)alloc((size_t)N_NODES * 256 * 4);     // [N,256] (reused, max H*Fout)
    float* h1 = (float*)alloc((size_t)N_NODES * 16 * 4);
    float* h2 = (float*)alloc((size_t)N_NODES * 32 * 4);
    float* h3 = (float*)alloc((size_t)N_NODES * 64 * 4);
    (void)ws_size;

    const int B = 256;
    int gN = (N_NODES + B - 1) / B;   // == NB
    int gE = (N_EDGES + B - 1) / B;

    // ---- build dst-CSR (no float atomics anywhere after this) ----
    zero_int_kernel<<<gN, B, 0, stream>>>(cnt, N_NODES);
    hist_kernel<<<gE, B, 0, stream>>>(dst, cnt);
    scan_block_kernel<<<NB, 256, 0, stream>>>(cnt, rowptr, blockSums);
    scan_sums_kernel<<<1, 512, 0, stream>>>(blockSums);
    add_offsets_kernel<<<NB, 256, 0, stream>>>(rowptr, blockSums);
    zero_int_kernel<<<gN, B, 0, stream>>>(cnt, N_NODES);
    scatter_kernel<<<gE, B, 0, stream>>>(src, dst, rowptr, cnt, csr_src);

    // ---- conv1: 16 -> 16 ----
    transform_kernel<16, 16><<<gN, B, 0, stream>>>(x, W1, U1, y, p);
    gather_kernel<16><<<(N_NODES * 16 + B - 1) / B, B, 0, stream>>>(rowptr, csr_src, y, p, c1, b1, h1);

    // ---- conv2: 16 -> 32 ----
    transform_kernel<16, 32><<<gN, B, 0, stream>>>(h1, W2, U2, y, p);
    gather_kernel<32><<<(N_NODES * 32 + B - 1) / B, B, 0, stream>>>(rowptr, csr_src, y, p, c2, b2, h2);

    // ---- conv3: 32 -> 64 ----
    transform_kernel<32, 64><<<gN, B, 0, stream>>>(h2, W3, U3, y, p);
    gather_kernel<64><<<(N_NODES * 64 + B - 1) / B, B, 0, stream>>>(rowptr, csr_src, y, p, c3, b3, h3);

    // ---- tail MLP ----
    tail_kernel<<<gN, B, 0, stream>>>(h3, lw1, lb1, lw2, lb2, lw3, lb3,
                                      lw4, lb4, lw5, lb5, (float*)d_out);
}

// Round 3
// 844.672 us; speedup vs baseline: 11.4168x; 1.0660x over previous
//
#include <hip/hip_runtime.h>
#include <math.h>

#define N_NODES 100000
#define N_EDGES 1600000
#define HEADS 4
#define NB ((N_NODES + 255) / 256)   // 391 scan blocks

// ---------------- CSR build kernels ----------------

__global__ void zero_int_kernel(int* __restrict__ ptr, int n) {
    int i = blockIdx.x * blockDim.x + threadIdx.x;
    if (i < n) ptr[i] = 0;
}

__global__ void hist_kernel(const int* __restrict__ dst, int* __restrict__ cnt) {
    int e = blockIdx.x * blockDim.x + threadIdx.x;
    if (e < N_EDGES) atomicAdd(&cnt[dst[e]], 1);
}

// per-block exclusive scan of cnt -> rowptr (block-local), block totals -> blockSums
__global__ __launch_bounds__(256) void scan_block_kernel(
        const int* __restrict__ cnt, int* __restrict__ rowptr, int* __restrict__ blockSums) {
    __shared__ int tmp[256];
    int i = blockIdx.x * 256 + threadIdx.x;
    int v = (i < N_NODES) ? cnt[i] : 0;
    tmp[threadIdx.x] = v;
    __syncthreads();
    for (int off = 1; off < 256; off <<= 1) {
        int t = (threadIdx.x >= off) ? tmp[threadIdx.x - off] : 0;
        __syncthreads();
        tmp[threadIdx.x] += t;
        __syncthreads();
    }
    if (i < N_NODES) rowptr[i] = tmp[threadIdx.x] - v;        // exclusive, block-local
    if (threadIdx.x == 255) blockSums[blockIdx.x] = tmp[255]; // inclusive block total
}

// single-block exclusive scan of blockSums (NB=391 <= 512)
__global__ __launch_bounds__(512) void scan_sums_kernel(int* __restrict__ blockSums) {
    __shared__ int tmp[512];
    int i = threadIdx.x;
    int v = (i < NB) ? blockSums[i] : 0;
    tmp[i] = v;
    __syncthreads();
    for (int off = 1; off < 512; off <<= 1) {
        int t = (i >= off) ? tmp[i - off] : 0;
        __syncthreads();
        tmp[i] += t;
        __syncthreads();
    }
    if (i < NB) blockSums[i] = tmp[i] - v;                    // exclusive
}

__global__ __launch_bounds__(256) void add_offsets_kernel(
        int* __restrict__ rowptr, const int* __restrict__ blockSums) {
    int i = blockIdx.x * 256 + threadIdx.x;
    if (i < N_NODES) rowptr[i] += blockSums[blockIdx.x];
    if (i == 0) rowptr[N_NODES] = N_EDGES;
}

__global__ void scatter_kernel(const int* __restrict__ src, const int* __restrict__ dst,
                               const int* __restrict__ rowptr, int* __restrict__ cnt,
                               int* __restrict__ csr_src, int* __restrict__ csr_dst) {
    int e = blockIdx.x * blockDim.x + threadIdx.x;
    if (e >= N_EDGES) return;
    int d = dst[e];
    int pos = rowptr[d] + atomicAdd(&cnt[d], 1);
    csr_src[pos] = src[e];
    csr_dst[pos] = d;
}

__global__ void invdeg_kernel(const int* __restrict__ rowptr, float* __restrict__ inv_deg) {
    int n = blockIdx.x * blockDim.x + threadIdx.x;
    if (n >= N_NODES) return;
    float d = (float)(rowptr[n + 1] - rowptr[n]);
    inv_deg[n] = 1.0f / fmaxf(d, 1.0f);
}

// ---------------- p = h @ U  [N,4] ----------------

template<int FIN>
__global__ __launch_bounds__(256) void p_kernel(
        const float* __restrict__ h, const float* __restrict__ U,  // [FIN,4]
        float* __restrict__ p)                                     // [N,4]
{
    int n = blockIdx.x * blockDim.x + threadIdx.x;
    if (n >= N_NODES) return;
    float a0 = 0, a1 = 0, a2 = 0, a3 = 0;
    const float* hr = h + (size_t)n * FIN;
    #pragma unroll
    for (int f = 0; f < FIN; f++) {
        float xv = hr[f];
        a0 += xv * U[f * 4 + 0];
        a1 += xv * U[f * 4 + 1];
        a2 += xv * U[f * 4 + 2];
        a3 += xv * U[f * 4 + 3];
    }
    *(float4*)(p + (size_t)n * 4) = make_float4(a0, a1, a2, a3);
}

// ---------------- q per CSR edge: softmax(p_s - p_d + c) * inv_deg[d] ----------------

__global__ __launch_bounds__(256) void q_kernel(
        const int* __restrict__ csr_src, const int* __restrict__ csr_dst,
        const float* __restrict__ p, const float* __restrict__ c,
        const float* __restrict__ inv_deg,
        float4* __restrict__ q_csr)
{
    int k = blockIdx.x * blockDim.x + threadIdx.x;
    if (k >= N_EDGES) return;
    int s = csr_src[k], d = csr_dst[k];
    float4 ps = *(const float4*)(p + (size_t)s * 4);
    float4 pd = *(const float4*)(p + (size_t)d * 4);
    float l0 = ps.x - pd.x + c[0];
    float l1 = ps.y - pd.y + c[1];
    float l2 = ps.z - pd.z + c[2];
    float l3 = ps.w - pd.w + c[3];
    float m = fmaxf(fmaxf(l0, l1), fmaxf(l2, l3));
    float q0 = expf(l0 - m), q1 = expf(l1 - m), q2 = expf(l2 - m), q3 = expf(l3 - m);
    float inv = inv_deg[d] / (q0 + q1 + q2 + q3);
    q_csr[k] = make_float4(q0 * inv, q1 * inv, q2 * inv, q3 * inv);
}

// ---------------- z gather: z[n][h*FIN+f] = sum_k q[k][h] * hprev[src_k][f] ----------------

template<int FIN>
__global__ __launch_bounds__(256) void zgather_kernel(
        const int* __restrict__ rowptr, const int* __restrict__ csr_src,
        const float4* __restrict__ q_csr,
        const float* __restrict__ hprev,   // [N, FIN]
        float* __restrict__ z)             // [N, 4*FIN]
{
    int t = blockIdx.x * blockDim.x + threadIdx.x;
    int n = t / FIN;
    int f = t - n * FIN;
    if (n >= N_NODES) return;
    int beg = rowptr[n], end = rowptr[n + 1];
    float a0 = 0, a1 = 0, a2 = 0, a3 = 0;
    for (int k = beg; k < end; k++) {
        int s = csr_src[k];              // broadcast within FIN-lane group
        float4 q = q_csr[k];             // broadcast
        float xv = hprev[(size_t)s * FIN + f];  // coalesced FIN-float segment
        a0 += q.x * xv; a1 += q.y * xv; a2 += q.z * xv; a3 += q.w * xv;
    }
    size_t base = (size_t)n * (4 * FIN) + f;
    z[base]           = a0;
    z[base + FIN]     = a1;
    z[base + 2 * FIN] = a2;
    z[base + 3 * FIN] = a3;
}

// ---------------- post: out[n,o] = relu( sum_{h,f} z[n,h*FIN+f]*W[f,h*FOUT+o] + b[o] ) ----

template<int FIN, int FOUT>
__global__ __launch_bounds__(256) void post_kernel(
        const float* __restrict__ z,    // [N, 4*FIN]
        const float* __restrict__ W,    // [FIN, 4*FOUT]
        const float* __restrict__ b,    // [FOUT]
        float* __restrict__ out)        // [N, FOUT]
{
    constexpr int WSZ = FIN * 4 * FOUT;
    __shared__ float Ws[WSZ];
    for (int i = threadIdx.x; i < WSZ; i += blockDim.x) Ws[i] = W[i];
    __syncthreads();

    int t = blockIdx.x * blockDim.x + threadIdx.x;
    int n = t / FOUT;
    int o = t - n * FOUT;
    if (n >= N_NODES) return;

    const float* zr = z + (size_t)n * (4 * FIN);
    float acc = b[o];
    #pragma unroll
    for (int h = 0; h < 4; h++) {
        #pragma unroll
        for (int f = 0; f < FIN; f++) {
            acc += zr[h * FIN + f] * Ws[f * (4 * FOUT) + h * FOUT + o];
        }
    }
    out[t] = fmaxf(acc, 0.0f);
}

// ---------------- fused linear tail: 64->32->16->8->4->1, relu..., sigmoid ----------------

__global__ __launch_bounds__(256) void tail_kernel(
        const float* __restrict__ h,   // [N, 64]
        const float* __restrict__ lw1, const float* __restrict__ lb1,
        const float* __restrict__ lw2, const float* __restrict__ lb2,
        const float* __restrict__ lw3, const float* __restrict__ lb3,
        const float* __restrict__ lw4, const float* __restrict__ lb4,
        const float* __restrict__ lw5, const float* __restrict__ lb5,
        float* __restrict__ out)
{
    __shared__ float w1[64 * 32], w2[32 * 16], w3[16 * 8], w4[8 * 4], w5[4];
    __shared__ float B1[32], B2[16], B3[8], B4[4], B5[1];
    for (int i = threadIdx.x; i < 64 * 32; i += blockDim.x) w1[i] = lw1[i];
    for (int i = threadIdx.x; i < 32 * 16; i += blockDim.x) w2[i] = lw2[i];
    for (int i = threadIdx.x; i < 16 * 8;  i += blockDim.x) w3[i] = lw3[i];
    for (int i = threadIdx.x; i < 8 * 4;   i += blockDim.x) w4[i] = lw4[i];
    for (int i = threadIdx.x; i < 4;       i += blockDim.x) w5[i] = lw5[i];
    for (int i = threadIdx.x; i < 32; i += blockDim.x) B1[i] = lb1[i];
    for (int i = threadIdx.x; i < 16; i += blockDim.x) B2[i] = lb2[i];
    for (int i = threadIdx.x; i < 8;  i += blockDim.x) B3[i] = lb3[i];
    for (int i = threadIdx.x; i < 4;  i += blockDim.x) B4[i] = lb4[i];
    if (threadIdx.x == 0) B5[0] = lb5[0];
    __syncthreads();

    int n = blockIdx.x * blockDim.x + threadIdx.x;
    if (n >= N_NODES) return;

    float a[64];
    #pragma unroll
    for (int i = 0; i < 64; i++) a[i] = h[(size_t)n * 64 + i];

    float t1[32];
    for (int o = 0; o < 32; o++) {
        float acc = B1[o];
        #pragma unroll
        for (int i = 0; i < 64; i++) acc += a[i] * w1[i * 32 + o];
        t1[o] = fmaxf(acc, 0.0f);
    }
    float t2[16];
    for (int o = 0; o < 16; o++) {
        float acc = B2[o];
        #pragma unroll
        for (int i = 0; i < 32; i++) acc += t1[i] * w2[i * 16 + o];
        t2[o] = fmaxf(acc, 0.0f);
    }
    float t3[8];
    for (int o = 0; o < 8; o++) {
        float acc = B3[o];
        #pragma unroll
        for (int i = 0; i < 16; i++) acc += t2[i] * w3[i * 8 + o];
        t3[o] = fmaxf(acc, 0.0f);
    }
    float t4[4];
    for (int o = 0; o < 4; o++) {
        float acc = B4[o];
        #pragma unroll
        for (int i = 0; i < 8; i++) acc += t3[i] * w4[i * 4 + o];
        t4[o] = fmaxf(acc, 0.0f);
    }
    float zf = B5[0];
    #pragma unroll
    for (int i = 0; i < 4; i++) zf += t4[i] * w5[i];
    out[n] = 1.0f / (1.0f + expf(-zf));
}

// ---------------- host launch ----------------

extern "C" void kernel_launch(void* const* d_in, const int* in_sizes, int n_in,
                              void* d_out, int out_size, void* d_ws, size_t ws_size,
                              hipStream_t stream) {
    const float* x   = (const float*)d_in[0];
    const int*   ei  = (const int*)d_in[1];
    const int*   src = ei;
    const int*   dst = ei + N_EDGES;
    const float* U1 = (const float*)d_in[2];  const float* c1 = (const float*)d_in[3];
    const float* W1 = (const float*)d_in[4];  const float* b1 = (const float*)d_in[5];
    const float* U2 = (const float*)d_in[6];  const float* c2 = (const float*)d_in[7];
    const float* W2 = (const float*)d_in[8];  const float* b2 = (const float*)d_in[9];
    const float* U3 = (const float*)d_in[10]; const float* c3 = (const float*)d_in[11];
    const float* W3 = (const float*)d_in[12]; const float* b3 = (const float*)d_in[13];
    const float* lw1 = (const float*)d_in[14]; const float* lb1 = (const float*)d_in[15];
    const float* lw2 = (const float*)d_in[16]; const float* lb2 = (const float*)d_in[17];
    const float* lw3 = (const float*)d_in[18]; const float* lb3 = (const float*)d_in[19];
    const float* lw4 = (const float*)d_in[20]; const float* lb4 = (const float*)d_in[21];
    const float* lw5 = (const float*)d_in[22]; const float* lb5 = (const float*)d_in[23];

    char* ws = (char*)d_ws;
    size_t off = 0;
    auto alloc = [&](size_t bytes) -> void* {
        void* ptr = (void*)(ws + off);
        off += (bytes + 255) & ~(size_t)255;
        return ptr;
    };
    int*    cnt       = (int*)alloc((size_t)N_NODES * 4);
    int*    rowptr    = (int*)alloc(((size_t)N_NODES + 1) * 4);
    int*    blockSums = (int*)alloc(512 * 4);
    int*    csr_src   = (int*)alloc((size_t)N_EDGES * 4);
    int*    csr_dst   = (int*)alloc((size_t)N_EDGES * 4);
    float*  inv_deg   = (float*)alloc((size_t)N_NODES * 4);
    float*  p         = (float*)alloc((size_t)N_NODES * 4 * 4);    // [N,4]
    float4* q_csr     = (float4*)alloc((size_t)N_EDGES * 16);      // [E,4]
    float*  z         = (float*)alloc((size_t)N_NODES * 128 * 4);  // [N,128] max
    float*  h1        = (float*)alloc((size_t)N_NODES * 16 * 4);
    float*  h2        = (float*)alloc((size_t)N_NODES * 32 * 4);
    float*  h3        = (float*)alloc((size_t)N_NODES * 64 * 4);
    (void)ws_size;

    const int B = 256;
    int gN = (N_NODES + B - 1) / B;   // == NB
    int gE = (N_EDGES + B - 1) / B;

    // ---- build dst-CSR ----
    zero_int_kernel<<<gN, B, 0, stream>>>(cnt, N_NODES);
    hist_kernel<<<gE, B, 0, stream>>>(dst, cnt);
    scan_block_kernel<<<NB, 256, 0, stream>>>(cnt, rowptr, blockSums);
    scan_sums_kernel<<<1, 512, 0, stream>>>(blockSums);
    add_offsets_kernel<<<NB, 256, 0, stream>>>(rowptr, blockSums);
    zero_int_kernel<<<gN, B, 0, stream>>>(cnt, N_NODES);
    scatter_kernel<<<gE, B, 0, stream>>>(src, dst, rowptr, cnt, csr_src, csr_dst);
    invdeg_kernel<<<gN, B, 0, stream>>>(rowptr, inv_deg);

    // ---- conv1: 16 -> 16 ----
    p_kernel<16><<<gN, B, 0, stream>>>(x, U1, p);
    q_kernel<<<gE, B, 0, stream>>>(csr_src, csr_dst, p, c1, inv_deg, q_csr);
    zgather_kernel<16><<<(N_NODES * 16 + B - 1) / B, B, 0, stream>>>(rowptr, csr_src, q_csr, x, z);
    post_kernel<16, 16><<<(N_NODES * 16 + B - 1) / B, B, 0, stream>>>(z, W1, b1, h1);

    // ---- conv2: 16 -> 32 ----
    p_kernel<16><<<gN, B, 0, stream>>>(h1, U2, p);
    q_kernel<<<gE, B, 0, stream>>>(csr_src, csr_dst, p, c2, inv_deg, q_csr);
    zgather_kernel<16><<<(N_NODES * 16 + B - 1) / B, B, 0, stream>>>(rowptr, csr_src, q_csr, h1, z);
    post_kernel<16, 32><<<(N_NODES * 32 + B - 1) / B, B, 0, stream>>>(z, W2, b2, h2);

    // ---- conv3: 32 -> 64 ----
    p_kernel<32><<<gN, B, 0, stream>>>(h2, U3, p);
    q_kernel<<<gE, B, 0, stream>>>(csr_src, csr_dst, p, c3, inv_deg, q_csr);
    zgather_kernel<32><<<(N_NODES * 32 + B - 1) / B, B, 0, stream>>>(rowptr, csr_src, q_csr, h2, z);
    post_kernel<32, 64><<<(N_NODES * 64 + B - 1) / B, B, 0, stream>>>(z, W3, b3, h3);

    // ---- tail MLP ----
    tail_kernel<<<gN, B, 0, stream>>>(h3, lw1, lb1, lw2, lb2, lw3, lb3,
                                      lw4, lb4, lw5, lb5, (float*)d_out);
}